// Round 12
// baseline (475.034 us; speedup 1.0000x reference)
//
#include <hip/hip_runtime.h>
#include <hip/hip_bf16.h>

typedef __attribute__((ext_vector_type(4))) float f32x4;
typedef __attribute__((ext_vector_type(8))) _Float16 f16x8; // MFMA f16 A/B frag
typedef __attribute__((ext_vector_type(16))) float f32x16;  // 32x32 MFMA C/D
typedef unsigned short u16;

#define NB 8
#define NE 256
#define NN 4096
#define SD 64

__device__ __forceinline__ f32x16 z16() {
  f32x16 v;
#pragma unroll
  for (int i = 0; i < 16; ++i) v[i] = 0.f;
  return v;
}
__device__ __forceinline__ void gload_lds16(const void* g, void* l) {
  __builtin_amdgcn_global_load_lds((const __attribute__((address_space(1))) void*)g,
                                   (__attribute__((address_space(3))) void*)l, 16, 0, 0);
}

// lane-half swap: a' = {a_lo, b_lo}, b' = {a_hi, b_hi} (T12)
#if __has_builtin(__builtin_amdgcn_permlane32_swap)
typedef int i32x2 __attribute__((ext_vector_type(2)));
__device__ __forceinline__ void plswap(int& a, int& b) {
  i32x2 r = __builtin_amdgcn_permlane32_swap(a, b, false, false);
  a = r[0]; b = r[1];
}
#else
__device__ __forceinline__ void plswap(int& a, int& b) {
  int xa = __shfl_xor(a, 32), xb = __shfl_xor(b, 32);
  int hi = (int)((threadIdx.x & 63) >> 5);
  int na = hi ? xb : a;
  int nb = hi ? b : xa;
  a = na; b = nb;
}
#endif

// ---------------- f32 -> f16 convert (conv input) ----------------
__global__ __launch_bounds__(256) void k_split(const float* __restrict__ x,
                                               u16* __restrict__ outF, int n4) {
  int i = blockIdx.x * 256 + threadIdx.x;
  if (i >= n4) return;
  float4 v = reinterpret_cast<const float4*>(x)[i];
  ushort4 o;
  o.x = __builtin_bit_cast(u16, (_Float16)v.x);
  o.y = __builtin_bit_cast(u16, (_Float16)v.y);
  o.z = __builtin_bit_cast(u16, (_Float16)v.z);
  o.w = __builtin_bit_cast(u16, (_Float16)v.w);
  reinterpret_cast<ushort4*>(outF)[i] = o;
}

// ------- convert + transpose conv weights: w[t][ei][eo] -> wT[t][eo][ei] (f16) -------
__global__ __launch_bounds__(256) void k_wsplit(const float* __restrict__ w,
                                                u16* __restrict__ wT) {
  int i = blockIdx.x * 256 + threadIdx.x;   // < 9*256*256
  int t = i >> 16;
  int r = i & 65535;
  int ei = r >> 8, eo = r & 255;
  int o = (t << 16) + (eo << 8) + ei;
  wT[o] = __builtin_bit_cast(u16, (_Float16)w[i]);
}

// ---------------- conv 3x3 implicit GEMM, single f16; epilogue -> f16 ----------------
// grid = 8b x 32mt x 2et; block 256 (4 waves 2x2, each 64pix x 64eo). LDS 36KB -> 3+ blocks/CU.
__global__ __launch_bounds__(256, 3) void k_conv(const u16* __restrict__ inF,
                                                 const u16* __restrict__ wT,
                                                 const float* __restrict__ bias,
                                                 u16* __restrict__ x1h) {
  __shared__ u16 Ah[128][72];
  __shared__ u16 Bh[128][72];
  int b = blockIdx.x >> 6;
  int rem = blockIdx.x & 63;
  int mt = rem >> 1, et = rem & 1;
  int h0 = mt << 1;
  int tid = threadIdx.x;
  int wid = tid >> 6, lane = tid & 63;
  int wr = wid >> 1, wc = wid & 1;
  int r = lane & 15, g = lane >> 4;
  f32x4 acc[4][4];
#pragma unroll
  for (int i = 0; i < 4; ++i)
#pragma unroll
    for (int j = 0; j < 4; ++j) acc[i][j] = (f32x4){0.f, 0.f, 0.f, 0.f};
  const long ibase = (long)b * NN * NE;

#pragma unroll 1
  for (int t = 0; t < 9; ++t) {
    int dy = t / 3 - 1, dx = t % 3 - 1;
#pragma unroll 1
    for (int kc = 0; kc < 4; ++kc) {
      __syncthreads();
      for (int c = tid; c < 1024; c += 256) {
        int pix = c >> 3, c8 = c & 7;
        int ww = pix & 63, hh = h0 + (pix >> 6);
        int sh = hh + dy, sw = ww + dx;
        float4 vh = make_float4(0.f, 0.f, 0.f, 0.f);
        if ((unsigned)sh < 64u && (unsigned)sw < 64u) {
          long off = ibase + ((long)sh * 64 + sw) * NE + kc * 64 + c8 * 8;
          vh = *reinterpret_cast<const float4*>(inF + off);
        }
        *reinterpret_cast<float4*>(&Ah[pix][c8 * 8]) = vh;
      }
      for (int c = tid; c < 1024; c += 256) {
        int eo = c >> 3, c8 = c & 7;
        long off = ((long)t << 16) + (et * 128 + eo) * 256 + kc * 64 + c8 * 8;
        *reinterpret_cast<float4*>(&Bh[eo][c8 * 8]) = *reinterpret_cast<const float4*>(wT + off);
      }
      __syncthreads();
#pragma unroll
      for (int ks = 0; ks < 2; ++ks) {
        int c8 = ks * 4 + g;
        f16x8 ah[4], bh[4];
#pragma unroll
        for (int mi = 0; mi < 4; ++mi)
          ah[mi] = *reinterpret_cast<const f16x8*>(&Ah[wr * 64 + mi * 16 + r][c8 * 8]);
#pragma unroll
        for (int ni = 0; ni < 4; ++ni)
          bh[ni] = *reinterpret_cast<const f16x8*>(&Bh[wc * 64 + ni * 16 + r][c8 * 8]);
#pragma unroll
        for (int mi = 0; mi < 4; ++mi)
#pragma unroll
          for (int ni = 0; ni < 4; ++ni)
            acc[mi][ni] = __builtin_amdgcn_mfma_f32_16x16x32_f16(ah[mi], bh[ni], acc[mi][ni], 0, 0, 0);
      }
    }
  }
#pragma unroll
  for (int mi = 0; mi < 4; ++mi)
#pragma unroll
    for (int ni = 0; ni < 4; ++ni) {
      int eo = et * 128 + wc * 64 + ni * 16 + r;
      float bz = bias[eo];
#pragma unroll
      for (int i = 0; i < 4; ++i) {
        int pix = mt * 128 + wr * 64 + mi * 16 + g * 4 + i;
        float v = acc[mi][ni][i] + bz;
        long o = ibase + (long)pix * NE + eo;
        x1h[o] = __builtin_bit_cast(u16, (_Float16)v);
      }
    }
}

// ---------------- transpose x1h[b][m][e] -> x1T[b][e][m] ----------------
__global__ __launch_bounds__(256) void k_trans(const u16* __restrict__ x1h, u16* __restrict__ x1T) {
  __shared__ u16 T[64][72];
  int bid = blockIdx.x;
  int b = bid >> 8, rem = bid & 255;
  int mt = rem >> 2, et = rem & 3;
  int tid = threadIdx.x;
  for (int c = tid; c < 512; c += 256) {
    int rr = c >> 3, c8 = c & 7;
    *reinterpret_cast<float4*>(&T[rr][c8 * 8]) =
        *reinterpret_cast<const float4*>(x1h + ((long)b * NN + mt * 64 + rr) * NE + et * 64 + c8 * 8);
  }
  __syncthreads();
  for (int c = tid; c < 512; c += 256) {
    int er = c >> 3, m8 = c & 7;
    union { u16 u[8]; float4 v; } p;
#pragma unroll
    for (int j = 0; j < 8; ++j) p.u[j] = T[m8 * 8 + j][er];
    *reinterpret_cast<float4*>(x1T + ((long)b * NE + et * 64 + er) * NN + mt * 64 + m8 * 8) = p.v;
  }
}

// ---------------- fused flash attention, f16, 32x32 MFMA, KVBLK=64, V-from-L2 ----------------
// grid 512 = 8b x 64 q-tiles of 64 rows (phys&7 = batch = XCD -> K/V L2-resident).
// block 256 = 4 waves: eh = wid&1 (output-dim half), qg = wid>>1; wave = 32q x 128e.
// LDS 64KB: K double-buffer 2x32KB ONLY. V is read directly from x1T (L2) in PV —
// each 64B V-line is one tile-row, zero over-fetch, no staging/barrier coupling.
// 64 iters, ONE barrier/iter: vmcnt(0)[K(it) landed]; barrier[QK(it-1) reads done];
// issue K(it+1); QK (32 MFMA, 2 chains); softmax(64kv); P-pack (R4 16-word pattern);
// PV (16 MFMA, V global loads with immediate-offset folds).
// K swz: byte ^ ((r&15)<<4) in 512B rows, source pre-swizzled (rule 21).
__global__ __launch_bounds__(256, 2) void k_flash4(const u16* __restrict__ x1h16,
                                                   const u16* __restrict__ x1T,
                                                   const float* __restrict__ inp,
                                                   float* __restrict__ out) {
  __shared__ char LDS[65536];
  int phys = blockIdx.x;
  int b = phys & 7;                             // batch == XCD
  int qt = phys >> 3;                           // q-tile of 64 rows (0..63)
  int tid = threadIdx.x, wid = tid >> 6, lane = tid & 63;
  int r31 = lane & 31, hi = lane >> 5;
  int eh = wid & 1, qg = wid >> 1;
  const long bN = (long)b << 12;
  const long vtb = (long)b << 20;

  // Q (f16) in regs: B-frag of S^T=mfma(K,Q): col=lane&31=qrow, k=hi*8+j
  const long qrow = bN + qt * 64 + qg * 32 + r31;
  f16x8 qh[16];
#pragma unroll
  for (int ks = 0; ks < 16; ++ks)
    qh[ks] = *reinterpret_cast<const f16x8*>(x1h16 + (qrow << 8) + ks * 16 + hi * 8);

  f32x16 o4[4];                                 // 128 output dims (eh half) = 64 regs
#pragma unroll
  for (int nf = 0; nf < 4; ++nf) o4[nf] = z16();
  float mrow = -1.0e30f, lrow = 0.f;

  // ---- K staging: per-thread constant chunk offsets + advancing base ----
  // 32 chunks of 1KB per 64-row tile; thread handles 8 (c = wid*8+i, 2 rows each).
  const u16* kBase = x1h16 + (bN << 8);         // u16 index advances by 16384/iter
  int kOff[8];
#pragma unroll
  for (int i = 0; i < 8; ++i) {
    int c = wid * 8 + i;
    int kr = c * 2 + (lane >> 5);
    int colb = ((lane & 31) << 4) ^ ((kr & 15) << 4);
    kOff[i] = (kr << 8) + (colb >> 1);
  }
  // ---- V row pointers (4, one per nf), advancing +64/iter; c-offset via imm fold ----
  const u16* vP[4];
#pragma unroll
  for (int nf = 0; nf < 4; ++nf) {
    int e = eh * 128 + nf * 32 + r31;
    vP[nf] = x1T + vtb + ((long)e << 12) + hi * 8;
  }

  // ---- prologue: stage K(0) -> buf0 ----
#pragma unroll
  for (int i = 0; i < 8; ++i)
    gload_lds16(kBase + kOff[i], LDS + ((wid * 8 + i) << 10));
  kBase += 16384;

#pragma unroll 1
  for (int it = 0; it < 64; ++it) {
    const char* KB = LDS + (it & 1) * 32768;

    asm volatile("s_waitcnt vmcnt(0)" ::: "memory");   // K(it) landed
    __builtin_amdgcn_s_barrier();                      // all waves: QK(it-1) reads done
    __builtin_amdgcn_sched_barrier(0);

    // ---- issue next K stage (hides under whole iteration) ----
    if (it < 63) {
      char* KD = LDS + ((it + 1) & 1) * 32768;
#pragma unroll
      for (int i = 0; i < 8; ++i)
        gload_lds16(kBase + kOff[i], KD + ((wid * 8 + i) << 10));
      kBase += 16384;
    }

    // ---- S^T = K.Q (64 kv x 32 q), two parallel chains (kv halves) ----
    f32x16 st0 = z16(), st1 = z16();
    int swzk = (r31 & 15) << 4;
    int krow0 = r31 << 9, krow1 = (32 + r31) << 9;
    __builtin_amdgcn_s_setprio(1);
#pragma unroll
    for (int ks = 0; ks < 16; ++ks) {
      int cby = (ks * 32 + hi * 16) ^ swzk;
      f16x8 k0 = *reinterpret_cast<const f16x8*>(KB + krow0 + cby);
      f16x8 k1 = *reinterpret_cast<const f16x8*>(KB + krow1 + cby);
      st0 = __builtin_amdgcn_mfma_f32_32x32x16_f16(k0, qh[ks], st0, 0, 0, 0);
      st1 = __builtin_amdgcn_mfma_f32_32x32x16_f16(k1, qh[ks], st1, 0, 0, 0);
    }
    __builtin_amdgcn_s_setprio(0);

    // ---- online softmax over 64 kv (qrow = lane&31; kv = (m&3)+8*(m>>2)+4*hi [+32]) ----
    float t8[8];
#pragma unroll
    for (int m = 0; m < 8; ++m) t8[m] = fmaxf(fmaxf(st0[m], st0[m + 8]), fmaxf(st1[m], st1[m + 8]));
    float t4a = fmaxf(t8[0], t8[4]), t4b = fmaxf(t8[1], t8[5]);
    float t4c = fmaxf(t8[2], t8[6]), t4d = fmaxf(t8[3], t8[7]);
    float tmax = fmaxf(fmaxf(t4a, t4b), fmaxf(t4c, t4d));
    tmax = fmaxf(tmax, __shfl_xor(tmax, 32));
    if (!__all(tmax <= mrow + 8.0f)) {          // defer-max (T13)
      float mnew = fmaxf(mrow, tmax);
      float alpha = __expf(mrow - mnew);
      lrow *= alpha;
      float ar[16];
#pragma unroll
      for (int m = 0; m < 16; ++m) ar[m] = __shfl(alpha, (m & 3) + 8 * (m >> 2) + 4 * hi);
#pragma unroll
      for (int nf = 0; nf < 4; ++nf)
#pragma unroll
        for (int m = 0; m < 16; ++m) o4[nf][m] *= ar[m];
      mrow = mnew;
    }
#pragma unroll
    for (int m = 0; m < 16; ++m) st0[m] = __expf(st0[m] - mrow);
#pragma unroll
    for (int m = 0; m < 16; ++m) st1[m] = __expf(st1[m] - mrow);
    float s8[8];
#pragma unroll
    for (int m = 0; m < 8; ++m) s8[m] = (st0[m] + st0[m + 8]) + (st1[m] + st1[m + 8]);
    float s4a = s8[0] + s8[4], s4b = s8[1] + s8[5], s4c = s8[2] + s8[6], s4d = s8[3] + s8[7];
    float psum = (s4a + s4b) + (s4c + s4d);
    psum += __shfl_xor(psum, 32);
    lrow += psum;

    // ---- P -> f16, re-fragment via permlane32_swap: 4 A-frags (kv chunks of 16) ----
    int Wd[16];
#pragma unroll
    for (int m = 0; m < 8; ++m) {
      unsigned l0 = __builtin_bit_cast(u16, (_Float16)st0[2 * m]);
      unsigned h0 = __builtin_bit_cast(u16, (_Float16)st0[2 * m + 1]);
      Wd[m] = (int)(l0 | (h0 << 16));
      unsigned l1 = __builtin_bit_cast(u16, (_Float16)st1[2 * m]);
      unsigned h1 = __builtin_bit_cast(u16, (_Float16)st1[2 * m + 1]);
      Wd[8 + m] = (int)(l1 | (h1 << 16));
    }
    plswap(Wd[0], Wd[2]);  plswap(Wd[1], Wd[3]);
    plswap(Wd[4], Wd[6]);  plswap(Wd[5], Wd[7]);
    plswap(Wd[8], Wd[10]); plswap(Wd[9], Wd[11]);
    plswap(Wd[12], Wd[14]); plswap(Wd[13], Wd[15]);
    union PU { int w[4]; f16x8 v; };
    PU pa[4];
#pragma unroll
    for (int c = 0; c < 4; ++c) {
      pa[c].w[0] = Wd[c * 4 + 0]; pa[c].w[1] = Wd[c * 4 + 1];
      pa[c].w[2] = Wd[c * 4 + 2]; pa[c].w[3] = Wd[c * 4 + 3];
    }

    // ---- O += P.V ; V straight from L2 (imm-offset folds: c*16 f16 = 32B) ----
    __builtin_amdgcn_s_setprio(1);
#pragma unroll
    for (int nf = 0; nf < 4; ++nf) {
      const f16x8* vr = reinterpret_cast<const f16x8*>(vP[nf]);
#pragma unroll
      for (int c = 0; c < 4; ++c) {
        f16x8 v = *reinterpret_cast<const f16x8*>(reinterpret_cast<const u16*>(vr) + c * 16);
        o4[nf] = __builtin_amdgcn_mfma_f32_32x32x16_f16(pa[c].v, v, o4[nf], 0, 0, 0);
      }
      vP[nf] += 64;
    }
    __builtin_amdgcn_s_setprio(0);
  }

  // ---- epilogue: /(16*l) * inp, direct store (waves own disjoint 32q x 128e) ----
  float linv = 1.0f / (16.0f * lrow);
  float lr[16];
#pragma unroll
  for (int m = 0; m < 16; ++m) lr[m] = __shfl(linv, (m & 3) + 8 * (m >> 2) + 4 * hi);
  const long ob = (bN + qt * 64 + qg * 32) << 8;
#pragma unroll
  for (int nf = 0; nf < 4; ++nf)
#pragma unroll
    for (int m = 0; m < 16; ++m) {
      int qr = (m & 3) + 8 * (m >> 2) + 4 * hi;
      long off2 = ob + ((long)qr << 8) + eh * 128 + nf * 32 + r31;
      out[off2] = o4[nf][m] * lr[m] * inp[off2];
    }
}

// ---------------- host ----------------
// ws layout (bytes):
//   [0,   16M)  x1h f16
//   [16M, 32M)  x1T f16
//   [32M, 48M)  inF f16 (conv temp)
//   [48M, +1.2M) wT f16 (conv temp)
extern "C" void kernel_launch(void* const* d_in, const int* in_sizes, int n_in,
                              void* d_out, int out_size, void* d_ws, size_t ws_size,
                              hipStream_t stream) {
  const float* inp   = (const float*)d_in[0];
  const float* convw = (const float*)d_in[1];
  const float* convb = (const float*)d_in[2];
  float* out = (float*)d_out;
  char* ws = (char*)d_ws;

  u16* x1h = (u16*)(ws);                   // f16
  u16* x1T = (u16*)(ws + 16777216L);       // f16, transposed
  u16* inF = (u16*)(ws + 33554432L);       // f16 conv input
  u16* wT  = (u16*)(ws + 50331648L);       // f16 transposed weights

  k_split<<<8192, 256, 0, stream>>>(inp, inF, 2097152);
  k_wsplit<<<2304, 256, 0, stream>>>(convw, wT);
  k_conv<<<512, 256, 0, stream>>>(inF, wT, convb, x1h);
  k_trans<<<2048, 256, 0, stream>>>(x1h, x1T);
  k_flash4<<<512, 256, 0, stream>>>(x1h, x1T, inp, out);
}

// Round 13
// 344.041 us; speedup vs baseline: 1.3807x; 1.3807x over previous
//
#include <hip/hip_runtime.h>
#include <hip/hip_bf16.h>

typedef __attribute__((ext_vector_type(4))) float f32x4;
typedef __attribute__((ext_vector_type(8))) _Float16 f16x8; // MFMA f16 A/B frag
typedef __attribute__((ext_vector_type(16))) float f32x16;  // 32x32 MFMA C/D
typedef unsigned short u16;

#define NB 8
#define NE 256
#define NN 4096
#define SD 64

__device__ __forceinline__ f32x16 z16() {
  f32x16 v;
#pragma unroll
  for (int i = 0; i < 16; ++i) v[i] = 0.f;
  return v;
}
__device__ __forceinline__ void gload_lds16(const void* g, void* l) {
  __builtin_amdgcn_global_load_lds((const __attribute__((address_space(1))) void*)g,
                                   (__attribute__((address_space(3))) void*)l, 16, 0, 0);
}
__device__ __forceinline__ float fexp2(float x) {
#if __has_builtin(__builtin_amdgcn_exp2f)
  return __builtin_amdgcn_exp2f(x);
#else
  return exp2f(x);
#endif
}

// lane-half swap: a' = {a_lo, b_lo}, b' = {a_hi, b_hi} (T12)
#if __has_builtin(__builtin_amdgcn_permlane32_swap)
typedef int i32x2 __attribute__((ext_vector_type(2)));
__device__ __forceinline__ void plswap(int& a, int& b) {
  i32x2 r = __builtin_amdgcn_permlane32_swap(a, b, false, false);
  a = r[0]; b = r[1];
}
#else
__device__ __forceinline__ void plswap(int& a, int& b) {
  int xa = __shfl_xor(a, 32), xb = __shfl_xor(b, 32);
  int hi = (int)((threadIdx.x & 63) >> 5);
  int na = hi ? xb : a;
  int nb = hi ? b : xa;
  a = na; b = nb;
}
#endif

// ---------------- f32 -> f16 convert (conv input) ----------------
__global__ __launch_bounds__(256) void k_split(const float* __restrict__ x,
                                               u16* __restrict__ outF, int n4) {
  int i = blockIdx.x * 256 + threadIdx.x;
  if (i >= n4) return;
  float4 v = reinterpret_cast<const float4*>(x)[i];
  ushort4 o;
  o.x = __builtin_bit_cast(u16, (_Float16)v.x);
  o.y = __builtin_bit_cast(u16, (_Float16)v.y);
  o.z = __builtin_bit_cast(u16, (_Float16)v.z);
  o.w = __builtin_bit_cast(u16, (_Float16)v.w);
  reinterpret_cast<ushort4*>(outF)[i] = o;
}

// ------- convert + transpose conv weights: w[t][ei][eo] -> wT[t][eo][ei] (f16) -------
__global__ __launch_bounds__(256) void k_wsplit(const float* __restrict__ w,
                                                u16* __restrict__ wT) {
  int i = blockIdx.x * 256 + threadIdx.x;   // < 9*256*256
  int t = i >> 16;
  int r = i & 65535;
  int ei = r >> 8, eo = r & 255;
  int o = (t << 16) + (eo << 8) + ei;
  wT[o] = __builtin_bit_cast(u16, (_Float16)w[i]);
}

// ---------------- conv 3x3 implicit GEMM, single f16; epilogue -> f16 ----------------
// grid = 8b x 32mt x 2et; block 256 (4 waves 2x2, each 64pix x 64eo). LDS 34KB.
// B staged via global_load_lds into linear BhL[128][64] with XOR swz ((eo&7)<<4),
// source pre-swizzled (rule 21); b-frag reads apply the same XOR (2-way = free).
// A keeps the padded flat-store path (border zeros need conditionals).
__global__ __launch_bounds__(256, 2) void k_conv(const u16* __restrict__ inF,
                                                 const u16* __restrict__ wT,
                                                 const float* __restrict__ bias,
                                                 u16* __restrict__ x1h) {
  __shared__ u16 Ah[128][72];
  __shared__ u16 BhL[128 * 64];
  int b = blockIdx.x >> 6;
  int rem = blockIdx.x & 63;
  int mt = rem >> 1, et = rem & 1;
  int h0 = mt << 1;
  int tid = threadIdx.x;
  int wid = tid >> 6, lane = tid & 63;
  int wr = wid >> 1, wc = wid & 1;
  int r = lane & 15, g = lane >> 4;
  f32x4 acc[4][4];
#pragma unroll
  for (int i = 0; i < 4; ++i)
#pragma unroll
    for (int j = 0; j < 4; ++j) acc[i][j] = (f32x4){0.f, 0.f, 0.f, 0.f};
  const long ibase = (long)b * NN * NE;
  // per-lane B source swizzle offset (f16 units) within a 128B eo-row
  const int bsw = ((((lane & 7) << 4) ^ (((lane >> 3) & 7) << 4)) >> 1);

#pragma unroll 1
  for (int t = 0; t < 9; ++t) {
    int dy = t / 3 - 1, dx = t % 3 - 1;
#pragma unroll 1
    for (int kc = 0; kc < 4; ++kc) {
      __syncthreads();
      // ---- stage A (conditional borders, padded rows) ----
      for (int c = tid; c < 1024; c += 256) {
        int pix = c >> 3, c8 = c & 7;
        int ww = pix & 63, hh = h0 + (pix >> 6);
        int sh = hh + dy, sw = ww + dx;
        float4 vh = make_float4(0.f, 0.f, 0.f, 0.f);
        if ((unsigned)sh < 64u && (unsigned)sw < 64u) {
          long off = ibase + ((long)sh * 64 + sw) * NE + kc * 64 + c8 * 8;
          vh = *reinterpret_cast<const float4*>(inF + off);
        }
        *reinterpret_cast<float4*>(&Ah[pix][c8 * 8]) = vh;
      }
      // ---- stage B via global_load_lds (16 chunks of 1KB = 8 eo-rows each) ----
#pragma unroll
      for (int i = 0; i < 4; ++i) {
        int c = wid * 4 + i;
        int eo = c * 8 + (lane >> 3);
        const u16* src = wT + ((long)t << 16) + (long)(et * 128 + eo) * 256 + kc * 64 + bsw;
        gload_lds16(src, (char*)BhL + c * 1024);
      }
      __syncthreads();
#pragma unroll
      for (int ks = 0; ks < 2; ++ks) {
        int c8 = ks * 4 + g;
        f16x8 ah[4], bh[4];
#pragma unroll
        for (int mi = 0; mi < 4; ++mi)
          ah[mi] = *reinterpret_cast<const f16x8*>(&Ah[wr * 64 + mi * 16 + r][c8 * 8]);
#pragma unroll
        for (int ni = 0; ni < 4; ++ni) {
          int col = wc * 64 + ni * 16 + r;
          int byteoff = (col << 7) + (((c8 << 4) ^ ((r & 7) << 4)));
          bh[ni] = *reinterpret_cast<const f16x8*>(reinterpret_cast<const char*>(BhL) + byteoff);
        }
#pragma unroll
        for (int mi = 0; mi < 4; ++mi)
#pragma unroll
          for (int ni = 0; ni < 4; ++ni)
            acc[mi][ni] = __builtin_amdgcn_mfma_f32_16x16x32_f16(ah[mi], bh[ni], acc[mi][ni], 0, 0, 0);
      }
    }
  }
#pragma unroll
  for (int mi = 0; mi < 4; ++mi)
#pragma unroll
    for (int ni = 0; ni < 4; ++ni) {
      int eo = et * 128 + wc * 64 + ni * 16 + r;
      float bz = bias[eo];
#pragma unroll
      for (int i = 0; i < 4; ++i) {
        int pix = mt * 128 + wr * 64 + mi * 16 + g * 4 + i;
        float v = acc[mi][ni][i] + bz;
        long o = ibase + (long)pix * NE + eo;
        x1h[o] = __builtin_bit_cast(u16, (_Float16)v);
      }
    }
}

// ---------------- transpose x1h[b][m][e] -> x1T[b][e][m] ----------------
__global__ __launch_bounds__(256) void k_trans(const u16* __restrict__ x1h, u16* __restrict__ x1T) {
  __shared__ u16 T[64][72];
  int bid = blockIdx.x;
  int b = bid >> 8, rem = bid & 255;
  int mt = rem >> 2, et = rem & 3;
  int tid = threadIdx.x;
  for (int c = tid; c < 512; c += 256) {
    int rr = c >> 3, c8 = c & 7;
    *reinterpret_cast<float4*>(&T[rr][c8 * 8]) =
        *reinterpret_cast<const float4*>(x1h + ((long)b * NN + mt * 64 + rr) * NE + et * 64 + c8 * 8);
  }
  __syncthreads();
  for (int c = tid; c < 512; c += 256) {
    int er = c >> 3, m8 = c & 7;
    union { u16 u[8]; float4 v; } p;
#pragma unroll
    for (int j = 0; j < 8; ++j) p.u[j] = T[m8 * 8 + j][er];
    *reinterpret_cast<float4*>(x1T + ((long)b * NE + et * 64 + er) * NN + mt * 64 + m8 * 8) = p.v;
  }
}

// ---------------- fused flash attention, f16, 32x32 MFMA, e-split, 1-barrier ----------------
// R11 structure (proven 268us) + exp2 domain: Q pre-scaled by log2e (f32 mul, re-rounded
// to f16 -> random noise only, no temperature bias); m/defer tracked in log2 domain
// (thr 8*log2e = 11.54); exp2 direct -> saves 32 v_mul/iter vs __expf.
// grid 512 = 8b x 64 q-tiles of 64 rows (phys&7 = batch = XCD). block 256 = 4 waves:
// eh = wid&1 (output-dim half), qg = wid>>1; o4 = 64 regs -> 2 blocks/CU.
// LDS 64KB: K dbuf 2x16KB @0, V dbuf 2x16KB @32K; ONE barrier/iter.
// K swz: byte ^ ((r&15)<<4) in 512B rows. V swz: bit6 row-pair swap + ((e&3)<<4).
__global__ __launch_bounds__(256, 2) void k_flash3(const u16* __restrict__ x1h16,
                                                   const u16* __restrict__ x1T,
                                                   const float* __restrict__ inp,
                                                   float* __restrict__ out) {
  __shared__ char LDS[65536];
  int phys = blockIdx.x;
  int b = phys & 7;                             // batch == XCD
  int qt = phys >> 3;                           // q-tile of 64 rows (0..63)
  int tid = threadIdx.x, wid = tid >> 6, lane = tid & 63;
  int r31 = lane & 31, hi = lane >> 5;
  int eh = wid & 1, qg = wid >> 1;
  const long bN = (long)b << 12;
  const long vtb = (long)b << 20;

  // Q (f16) in regs, pre-scaled by log2e in f32 (exp2 domain)
  const long qrow = bN + qt * 64 + qg * 32 + r31;
  f16x8 qh[16];
#pragma unroll
  for (int ks = 0; ks < 16; ++ks) {
    qh[ks] = *reinterpret_cast<const f16x8*>(x1h16 + (qrow << 8) + ks * 16 + hi * 8);
#pragma unroll
    for (int j = 0; j < 8; ++j)
      qh[ks][j] = (_Float16)((float)qh[ks][j] * 1.44269504f);
  }

  f32x16 o4[4];                                 // 128 output dims (eh half) = 64 regs
#pragma unroll
  for (int nf = 0; nf < 4; ++nf) o4[nf] = z16();
  float mrow = -1.0e30f, lrow = 0.f;

  // ---- precompute staging source pointers (kv0 = 0) and LDS chunk offsets ----
  const u16* kS[4];
  const u16* vS[4];
  int off[4];
#pragma unroll
  for (int i = 0; i < 4; ++i) {
    int c = wid * 4 + i;
    off[i] = c << 10;
    int kr = c * 2 + (lane >> 5);
    int kcolb = ((lane & 31) << 4) ^ ((kr & 15) << 4);
    kS[i] = x1h16 + ((bN + kr) << 8) + (kcolb >> 1);
    int rp = c * 16 + (lane >> 2);
    int e = rp ^ ((rp >> 2) & 1);               // involutive row-pair swap
    int vcolb = ((lane & 3) << 4) ^ ((e & 3) << 4);
    vS[i] = x1T + vtb + ((long)e << 12) + (vcolb >> 1);
  }

  // ---- prologue: stage K,V(0) -> buf0; pointers advance to it=1 ----
#pragma unroll
  for (int i = 0; i < 4; ++i) { gload_lds16(kS[i], LDS + off[i]); kS[i] += 8192; }
#pragma unroll
  for (int i = 0; i < 4; ++i) { gload_lds16(vS[i], LDS + 32768 + off[i]); vS[i] += 32; }

#pragma unroll 1
  for (int it = 0; it < 128; ++it) {
    const char* KB = LDS + (it & 1) * 16384;
    const char* VB = LDS + 32768 + (it & 1) * 16384;

    asm volatile("s_waitcnt vmcnt(0)" ::: "memory");   // K,V(it) landed
    __builtin_amdgcn_s_barrier();                      // all waves: (it) ready, PV(it-1) done
    __builtin_amdgcn_sched_barrier(0);

    // ---- issue next stages first: whole iteration hides the latency ----
    if (it < 127) {
      char* KD = LDS + ((it + 1) & 1) * 16384;
      char* VD = LDS + 32768 + ((it + 1) & 1) * 16384;
#pragma unroll
      for (int i = 0; i < 4; ++i) { gload_lds16(kS[i], KD + off[i]); kS[i] += 8192; }
#pragma unroll
      for (int i = 0; i < 4; ++i) { gload_lds16(vS[i], VD + off[i]); vS[i] += 32; }
    }

    // ---- S^T = K.Q (32 kv x 32 q), two parallel chains ----
    f32x16 stA = z16(), stB = z16();
    int swzk = (r31 & 15) << 4;
    int krow = r31 << 9;
    __builtin_amdgcn_s_setprio(1);
#pragma unroll
    for (int ks = 0; ks < 8; ++ks) {
      int cbyA = ((2 * ks) * 32 + hi * 16) ^ swzk;
      int cbyB = ((2 * ks + 1) * 32 + hi * 16) ^ swzk;
      f16x8 kA = *reinterpret_cast<const f16x8*>(KB + krow + cbyA);
      f16x8 kB = *reinterpret_cast<const f16x8*>(KB + krow + cbyB);
      stA = __builtin_amdgcn_mfma_f32_32x32x16_f16(kA, qh[2 * ks], stA, 0, 0, 0);
      stB = __builtin_amdgcn_mfma_f32_32x32x16_f16(kB, qh[2 * ks + 1], stB, 0, 0, 0);
    }
    __builtin_amdgcn_s_setprio(0);
    f32x16 st;
#pragma unroll
    for (int m = 0; m < 16; ++m) st[m] = stA[m] + stB[m];

    // ---- online softmax in log2 domain (qrow = lane&31), tree reduces ----
    float t8[8];
#pragma unroll
    for (int m = 0; m < 8; ++m) t8[m] = fmaxf(st[m], st[m + 8]);
    float t4a = fmaxf(t8[0], t8[4]), t4b = fmaxf(t8[1], t8[5]);
    float t4c = fmaxf(t8[2], t8[6]), t4d = fmaxf(t8[3], t8[7]);
    float tmax = fmaxf(fmaxf(t4a, t4b), fmaxf(t4c, t4d));
    tmax = fmaxf(tmax, __shfl_xor(tmax, 32));
    if (!__all(tmax <= mrow + 11.54f)) {        // defer-max (T13), 8*log2e
      float mnew = fmaxf(mrow, tmax);
      float alpha = fexp2(mrow - mnew);
      lrow *= alpha;
      float ar[16];
#pragma unroll
      for (int m = 0; m < 16; ++m) ar[m] = __shfl(alpha, (m & 3) + 8 * (m >> 2) + 4 * hi);
#pragma unroll
      for (int nf = 0; nf < 4; ++nf)
#pragma unroll
        for (int m = 0; m < 16; ++m) o4[nf][m] *= ar[m];
      mrow = mnew;
    }
#pragma unroll
    for (int m = 0; m < 16; ++m) st[m] = fexp2(st[m] - mrow);
    float s8[8];
#pragma unroll
    for (int m = 0; m < 8; ++m) s8[m] = st[m] + st[m + 8];
    float s4a = s8[0] + s8[4], s4b = s8[1] + s8[5], s4c = s8[2] + s8[6], s4d = s8[3] + s8[7];
    float psum = (s4a + s4b) + (s4c + s4d);
    psum += __shfl_xor(psum, 32);
    lrow += psum;

    // ---- P -> f16, re-fragment via permlane32_swap: 2 A-frags (kv chunks of 16) ----
    int Wd[8];
#pragma unroll
    for (int m = 0; m < 8; ++m) {
      unsigned l0 = __builtin_bit_cast(u16, (_Float16)st[2 * m]);
      unsigned h0 = __builtin_bit_cast(u16, (_Float16)st[2 * m + 1]);
      Wd[m] = (int)(l0 | (h0 << 16));
    }
    plswap(Wd[0], Wd[2]); plswap(Wd[1], Wd[3]);
    plswap(Wd[4], Wd[6]); plswap(Wd[5], Wd[7]);
    union PU { int w[4]; f16x8 v; };
    PU pa[2];
#pragma unroll
    for (int c = 0; c < 2; ++c) {
      pa[c].w[0] = Wd[c * 4 + 0]; pa[c].w[1] = Wd[c * 4 + 1];
      pa[c].w[2] = Wd[c * 4 + 2]; pa[c].w[3] = Wd[c * 4 + 3];
    }

    // ---- O += P.V over this wave's e-half (V(it) resident) ----
    __builtin_amdgcn_s_setprio(1);
#pragma unroll
    for (int nf = 0; nf < 4; ++nf) {
      int e = eh * 128 + nf * 32 + r31;
      const char* vrow = VB + ((e << 6) ^ ((e & 4) << 4));   // bit6 row-pair swap
      int swzv = (e & 3) << 4;
#pragma unroll
      for (int c = 0; c < 2; ++c) {
        f16x8 v = *reinterpret_cast<const f16x8*>(vrow + ((c * 32 + hi * 16) ^ swzv));
        o4[nf] = __builtin_amdgcn_mfma_f32_32x32x16_f16(pa[c].v, v, o4[nf], 0, 0, 0);
      }
    }
    __builtin_amdgcn_s_setprio(0);
  }

  // ---- epilogue: /(16*l) * inp, direct store (waves own disjoint 32q x 128e) ----
  float linv = 1.0f / (16.0f * lrow);
  float lr[16];
#pragma unroll
  for (int m = 0; m < 16; ++m) lr[m] = __shfl(linv, (m & 3) + 8 * (m >> 2) + 4 * hi);
  const long ob = (bN + qt * 64 + qg * 32) << 8;
#pragma unroll
  for (int nf = 0; nf < 4; ++nf)
#pragma unroll
    for (int m = 0; m < 16; ++m) {
      int qr = (m & 3) + 8 * (m >> 2) + 4 * hi;
      long off2 = ob + ((long)qr << 8) + eh * 128 + nf * 32 + r31;
      out[off2] = o4[nf][m] * lr[m] * inp[off2];
    }
}

// ---------------- host ----------------
// ws layout (bytes):
//   [0,   16M)  x1h f16
//   [16M, 32M)  x1T f16
//   [32M, 48M)  inF f16 (conv temp)
//   [48M, +1.2M) wT f16 (conv temp)
extern "C" void kernel_launch(void* const* d_in, const int* in_sizes, int n_in,
                              void* d_out, int out_size, void* d_ws, size_t ws_size,
                              hipStream_t stream) {
  const float* inp   = (const float*)d_in[0];
  const float* convw = (const float*)d_in[1];
  const float* convb = (const float*)d_in[2];
  float* out = (float*)d_out;
  char* ws = (char*)d_ws;

  u16* x1h = (u16*)(ws);                   // f16
  u16* x1T = (u16*)(ws + 16777216L);       // f16, transposed
  u16* inF = (u16*)(ws + 33554432L);       // f16 conv input
  u16* wT  = (u16*)(ws + 50331648L);       // f16 transposed weights

  k_split<<<8192, 256, 0, stream>>>(inp, inF, 2097152);
  k_wsplit<<<2304, 256, 0, stream>>>(convw, wT);
  k_conv<<<512, 256, 0, stream>>>(inF, wT, convb, x1h);
  k_trans<<<2048, 256, 0, stream>>>(x1h, x1T);
  k_flash3<<<512, 256, 0, stream>>>(x1h, x1T, inp, out);
}

// Round 14
// 306.802 us; speedup vs baseline: 1.5483x; 1.1214x over previous
//
#include <hip/hip_runtime.h>
#include <hip/hip_bf16.h>

typedef __attribute__((ext_vector_type(4))) float f32x4;
typedef __attribute__((ext_vector_type(8))) _Float16 f16x8; // MFMA f16 A/B frag
typedef __attribute__((ext_vector_type(16))) float f32x16;  // 32x32 MFMA C/D
typedef unsigned short u16;

#define NB 8
#define NE 256
#define NN 4096
#define SD 64

__device__ __forceinline__ f32x16 z16() {
  f32x16 v;
#pragma unroll
  for (int i = 0; i < 16; ++i) v[i] = 0.f;
  return v;
}
__device__ __forceinline__ void gload_lds16(const void* g, void* l) {
  __builtin_amdgcn_global_load_lds((const __attribute__((address_space(1))) void*)g,
                                   (__attribute__((address_space(3))) void*)l, 16, 0, 0);
}
__device__ __forceinline__ float fexp2(float x) {
#if __has_builtin(__builtin_amdgcn_exp2f)
  return __builtin_amdgcn_exp2f(x);
#else
  return exp2f(x);
#endif
}

// lane-half swap: a' = {a_lo, b_lo}, b' = {a_hi, b_hi} (T12)
#if __has_builtin(__builtin_amdgcn_permlane32_swap)
typedef int i32x2 __attribute__((ext_vector_type(2)));
__device__ __forceinline__ void plswap(int& a, int& b) {
  i32x2 r = __builtin_amdgcn_permlane32_swap(a, b, false, false);
  a = r[0]; b = r[1];
}
#else
__device__ __forceinline__ void plswap(int& a, int& b) {
  int xa = __shfl_xor(a, 32), xb = __shfl_xor(b, 32);
  int hi = (int)((threadIdx.x & 63) >> 5);
  int na = hi ? xb : a;
  int nb = hi ? b : xa;
  a = na; b = nb;
}
#endif

// ------- merged prep: f32->f16 input convert (bid<8192) + weight convert/transpose -------
__global__ __launch_bounds__(256) void k_prep(const float* __restrict__ x, u16* __restrict__ outF,
                                              const float* __restrict__ w, u16* __restrict__ wT) {
  int bid = blockIdx.x;
  int tid = threadIdx.x;
  if (bid < 8192) {
    int i = bid * 256 + tid;                    // float4 index < 2097152
    float4 v = reinterpret_cast<const float4*>(x)[i];
    ushort4 o;
    o.x = __builtin_bit_cast(u16, (_Float16)v.x);
    o.y = __builtin_bit_cast(u16, (_Float16)v.y);
    o.z = __builtin_bit_cast(u16, (_Float16)v.z);
    o.w = __builtin_bit_cast(u16, (_Float16)v.w);
    reinterpret_cast<ushort4*>(outF)[i] = o;
  } else {
    int i = (bid - 8192) * 256 + tid;           // < 9*256*256 = 589824
    int t = i >> 16;
    int r = i & 65535;
    int ei = r >> 8, eo = r & 255;
    int o = (t << 16) + (eo << 8) + ei;
    wT[o] = __builtin_bit_cast(u16, (_Float16)w[i]);
  }
}

// ---------------- conv 3x3 implicit GEMM, f16, halo-staged A ----------------
// grid = 8b x 32mt x 2et; block 256 (4 waves 2x2, each 64pix x 64eo). LDS 65.8KB -> 2 blocks/CU.
// Loop order: kc outer (4 x 64-ei chunks), tap t inner (9). A staged ONCE per kc as a
// 4-row x 66-col halo tile (rows h0-1..h0+2, cols -1..64) via global_load_lds with
// CLAMPED addresses, then halo slots zeroed by ds_write. All 9 taps read the same tile
// at slot = (wr+1+dy)*66 + (mi*16+r) + 1+dx. Slot-swizzle: byte = slot*128 + (c8*16 ^
// ((slot&7)<<4)) -> 2 lanes/bank (free). B: gload_lds dbuf, parity gidx=kc*9+t,
// 1 barrier per t-iter (t=0 covered by the A-barrier). Raw s_barrier + counted waits
// (no __syncthreads vmcnt drain).
__global__ __launch_bounds__(256, 2) void k_conv(const u16* __restrict__ inF,
                                                 const u16* __restrict__ wT,
                                                 const float* __restrict__ bias,
                                                 u16* __restrict__ x1h) {
  __shared__ u16 Ahalo[264 * 64];               // 33 chunks of 1KB (slot = chunk*8 + lane>>3)
  __shared__ u16 BhL[2][128 * 64];              // B dbuf 2x16KB, swz ((eo&7)<<4)
  int b = blockIdx.x >> 6;
  int rem = blockIdx.x & 63;
  int mt = rem >> 1, et = rem & 1;
  int h0 = mt << 1;
  int tid = threadIdx.x;
  int wid = tid >> 6, lane = tid & 63;
  int wr = wid >> 1, wc = wid & 1;
  int r = lane & 15, g = lane >> 4;
  f32x4 acc[4][4];
#pragma unroll
  for (int i = 0; i < 4; ++i)
#pragma unroll
    for (int j = 0; j < 4; ++j) acc[i][j] = (f32x4){0.f, 0.f, 0.f, 0.f};
  const long ibase = (long)b * NN * NE;

  // B staging per-thread source offsets (4 chunks of 1KB = 8 eo-rows each)
  const int bsw = ((((lane & 7) << 4) ^ (((lane >> 3) & 7) << 4)) >> 1);  // f16 units
  long bSrc[4];
#pragma unroll
  for (int i = 0; i < 4; ++i) {
    int c = wid * 4 + i;
    int eo = c * 8 + (lane >> 3);
    bSrc[i] = (long)(et * 128 + eo) * 256 + bsw;
  }
  // A staging: wave w handles chunks c = w + 4j (c < 33); slot = c*8 + (lane>>3)
  int aSlot[9], aHalo[9];
  const u16* aSrc[9];
#pragma unroll
  for (int j = 0; j < 9; ++j) {
    int c = wid + 4 * j;
    int slot = c * 8 + (lane >> 3);
    int hr = slot >= 198 ? 3 : (slot >= 132 ? 2 : (slot >= 66 ? 1 : 0));
    int hc = slot - hr * 66;
    int ir = h0 - 1 + hr, ic = hc - 1;
    aHalo[j] = ((unsigned)ir >= 64u) | ((unsigned)ic >= 64u);
    int irc = min(max(ir, 0), 63), icc = min(max(ic, 0), 63);
    int c8s = (lane & 7) ^ (slot & 7);          // pre-swizzled ei chunk
    aSlot[j] = slot;
    aSrc[j] = inF + ibase + ((long)(irc * 64 + icc) << 8) + c8s * 8;
  }

  // prologue: B(0,0) -> buf0
#pragma unroll
  for (int i = 0; i < 4; ++i)
    gload_lds16(wT + bSrc[i], (char*)BhL[0] + (wid * 4 + i) * 1024);

#pragma unroll 1
  for (int kc = 0; kc < 4; ++kc) {
    __builtin_amdgcn_s_barrier();               // all prev-kc A reads done
    // ---- stage A halo (clamped gload_lds) ----
#pragma unroll
    for (int j = 0; j < 9; ++j) {
      int c = wid + 4 * j;
      if (c < 33)                               // wave-uniform
        gload_lds16(aSrc[j] + kc * 64, (char*)Ahalo + c * 1024);
    }
    asm volatile("s_waitcnt vmcnt(0)" ::: "memory");   // A landed (and pending B drained)
    // ---- zero halo slots ----
#pragma unroll
    for (int j = 0; j < 9; ++j) {
      int c = wid + 4 * j;
      if (c < 33 && aHalo[j])
        *reinterpret_cast<float4*>((char*)Ahalo + c * 1024 + (lane << 4)) =
            make_float4(0.f, 0.f, 0.f, 0.f);
    }
    asm volatile("s_waitcnt lgkmcnt(0)" ::: "memory");
    __builtin_amdgcn_s_barrier();               // A(kc) visible

#pragma unroll 1
    for (int t = 0; t < 9; ++t) {
      int gidx = kc * 9 + t;
      if (t > 0) {
        asm volatile("s_waitcnt vmcnt(0)" ::: "memory");  // B(kc,t) landed
        __builtin_amdgcn_s_barrier();
      }
      // issue next B (lands during this t's MFMA + next barrier)
      if (gidx < 35) {
        int nt = t + 1 == 9 ? 0 : t + 1;
        int nkc = t + 1 == 9 ? kc + 1 : kc;
        long tkoff = ((long)nt << 16) + nkc * 64;
        char* dstB = (char*)BhL[(gidx + 1) & 1];
#pragma unroll
        for (int i = 0; i < 4; ++i)
          gload_lds16(wT + tkoff + bSrc[i], dstB + (wid * 4 + i) * 1024);
      }
      const u16* BB = BhL[gidx & 1];
      int dy = t / 3 - 1, dx = t % 3 - 1;
      int abase = (wr + 1 + dy) * 66 + 1 + dx;  // + mi*16 + r
#pragma unroll
      for (int ks = 0; ks < 2; ++ks) {
        int c8 = ks * 4 + g;
        f16x8 ah[4], bh[4];
#pragma unroll
        for (int mi = 0; mi < 4; ++mi) {
          int slot = abase + mi * 16 + r;
          int abyte = (slot << 7) + ((c8 << 4) ^ ((slot & 7) << 4));
          ah[mi] = *reinterpret_cast<const f16x8*>(reinterpret_cast<const char*>(Ahalo) + abyte);
        }
#pragma unroll
        for (int ni = 0; ni < 4; ++ni) {
          int col = wc * 64 + ni * 16 + r;
          int bbyte = (col << 7) + ((c8 << 4) ^ ((r & 7) << 4));
          bh[ni] = *reinterpret_cast<const f16x8*>(reinterpret_cast<const char*>(BB) + bbyte);
        }
#pragma unroll
        for (int mi = 0; mi < 4; ++mi)
#pragma unroll
          for (int ni = 0; ni < 4; ++ni)
            acc[mi][ni] = __builtin_amdgcn_mfma_f32_16x16x32_f16(ah[mi], bh[ni], acc[mi][ni], 0, 0, 0);
      }
    }
  }
  // ---- epilogue: +bias -> f16 ----
#pragma unroll
  for (int mi = 0; mi < 4; ++mi)
#pragma unroll
    for (int ni = 0; ni < 4; ++ni) {
      int eo = et * 128 + wc * 64 + ni * 16 + r;
      float bz = bias[eo];
#pragma unroll
      for (int i = 0; i < 4; ++i) {
        int pix = mt * 128 + wr * 64 + mi * 16 + g * 4 + i;
        float v = acc[mi][ni][i] + bz;
        long o = ibase + (long)pix * NE + eo;
        x1h[o] = __builtin_bit_cast(u16, (_Float16)v);
      }
    }
}

// ---------------- transpose x1h[b][m][e] -> x1T[b][e][m] ----------------
__global__ __launch_bounds__(256) void k_trans(const u16* __restrict__ x1h, u16* __restrict__ x1T) {
  __shared__ u16 T[64][72];
  int bid = blockIdx.x;
  int b = bid >> 8, rem = bid & 255;
  int mt = rem >> 2, et = rem & 3;
  int tid = threadIdx.x;
  for (int c = tid; c < 512; c += 256) {
    int rr = c >> 3, c8 = c & 7;
    *reinterpret_cast<float4*>(&T[rr][c8 * 8]) =
        *reinterpret_cast<const float4*>(x1h + ((long)b * NN + mt * 64 + rr) * NE + et * 64 + c8 * 8);
  }
  __syncthreads();
  for (int c = tid; c < 512; c += 256) {
    int er = c >> 3, m8 = c & 7;
    union { u16 u[8]; float4 v; } p;
#pragma unroll
    for (int j = 0; j < 8; ++j) p.u[j] = T[m8 * 8 + j][er];
    *reinterpret_cast<float4*>(x1T + ((long)b * NE + et * 64 + er) * NN + mt * 64 + m8 * 8) = p.v;
  }
}

// ---------------- fused flash attention (R13-exact, proven 267us) ----------------
__global__ __launch_bounds__(256, 2) void k_flash3(const u16* __restrict__ x1h16,
                                                   const u16* __restrict__ x1T,
                                                   const float* __restrict__ inp,
                                                   float* __restrict__ out) {
  __shared__ char LDS[65536];
  int phys = blockIdx.x;
  int b = phys & 7;                             // batch == XCD
  int qt = phys >> 3;                           // q-tile of 64 rows (0..63)
  int tid = threadIdx.x, wid = tid >> 6, lane = tid & 63;
  int r31 = lane & 31, hi = lane >> 5;
  int eh = wid & 1, qg = wid >> 1;
  const long bN = (long)b << 12;
  const long vtb = (long)b << 20;

  // Q (f16) in regs, pre-scaled by log2e in f32 (exp2 domain)
  const long qrow = bN + qt * 64 + qg * 32 + r31;
  f16x8 qh[16];
#pragma unroll
  for (int ks = 0; ks < 16; ++ks) {
    qh[ks] = *reinterpret_cast<const f16x8*>(x1h16 + (qrow << 8) + ks * 16 + hi * 8);
#pragma unroll
    for (int j = 0; j < 8; ++j)
      qh[ks][j] = (_Float16)((float)qh[ks][j] * 1.44269504f);
  }

  f32x16 o4[4];                                 // 128 output dims (eh half) = 64 regs
#pragma unroll
  for (int nf = 0; nf < 4; ++nf) o4[nf] = z16();
  float mrow = -1.0e30f, lrow = 0.f;

  // ---- precompute staging source pointers (kv0 = 0) and LDS chunk offsets ----
  const u16* kS[4];
  const u16* vS[4];
  int off[4];
#pragma unroll
  for (int i = 0; i < 4; ++i) {
    int c = wid * 4 + i;
    off[i] = c << 10;
    int kr = c * 2 + (lane >> 5);
    int kcolb = ((lane & 31) << 4) ^ ((kr & 15) << 4);
    kS[i] = x1h16 + ((bN + kr) << 8) + (kcolb >> 1);
    int rp = c * 16 + (lane >> 2);
    int e = rp ^ ((rp >> 2) & 1);               // involutive row-pair swap
    int vcolb = ((lane & 3) << 4) ^ ((e & 3) << 4);
    vS[i] = x1T + vtb + ((long)e << 12) + (vcolb >> 1);
  }

  // ---- prologue: stage K,V(0) -> buf0; pointers advance to it=1 ----
#pragma unroll
  for (int i = 0; i < 4; ++i) { gload_lds16(kS[i], LDS + off[i]); kS[i] += 8192; }
#pragma unroll
  for (int i = 0; i < 4; ++i) { gload_lds16(vS[i], LDS + 32768 + off[i]); vS[i] += 32; }

#pragma unroll 1
  for (int it = 0; it < 128; ++it) {
    const char* KB = LDS + (it & 1) * 16384;
    const char* VB = LDS + 32768 + (it & 1) * 16384;

    asm volatile("s_waitcnt vmcnt(0)" ::: "memory");   // K,V(it) landed
    __builtin_amdgcn_s_barrier();                      // all waves: (it) ready, PV(it-1) done
    __builtin_amdgcn_sched_barrier(0);

    // ---- issue next stages first: whole iteration hides the latency ----
    if (it < 127) {
      char* KD = LDS + ((it + 1) & 1) * 16384;
      char* VD = LDS + 32768 + ((it + 1) & 1) * 16384;
#pragma unroll
      for (int i = 0; i < 4; ++i) { gload_lds16(kS[i], KD + off[i]); kS[i] += 8192; }
#pragma unroll
      for (int i = 0; i < 4; ++i) { gload_lds16(vS[i], VD + off[i]); vS[i] += 32; }
    }

    // ---- S^T = K.Q (32 kv x 32 q), two parallel chains ----
    f32x16 stA = z16(), stB = z16();
    int swzk = (r31 & 15) << 4;
    int krow = r31 << 9;
    __builtin_amdgcn_s_setprio(1);
#pragma unroll
    for (int ks = 0; ks < 8; ++ks) {
      int cbyA = ((2 * ks) * 32 + hi * 16) ^ swzk;
      int cbyB = ((2 * ks + 1) * 32 + hi * 16) ^ swzk;
      f16x8 kA = *reinterpret_cast<const f16x8*>(KB + krow + cbyA);
      f16x8 kB = *reinterpret_cast<const f16x8*>(KB + krow + cbyB);
      stA = __builtin_amdgcn_mfma_f32_32x32x16_f16(kA, qh[2 * ks], stA, 0, 0, 0);
      stB = __builtin_amdgcn_mfma_f32_32x32x16_f16(kB, qh[2 * ks + 1], stB, 0, 0, 0);
    }
    __builtin_amdgcn_s_setprio(0);
    f32x16 st;
#pragma unroll
    for (int m = 0; m < 16; ++m) st[m] = stA[m] + stB[m];

    // ---- online softmax in log2 domain (qrow = lane&31), tree reduces ----
    float t8[8];
#pragma unroll
    for (int m = 0; m < 8; ++m) t8[m] = fmaxf(st[m], st[m + 8]);
    float t4a = fmaxf(t8[0], t8[4]), t4b = fmaxf(t8[1], t8[5]);
    float t4c = fmaxf(t8[2], t8[6]), t4d = fmaxf(t8[3], t8[7]);
    float tmax = fmaxf(fmaxf(t4a, t4b), fmaxf(t4c, t4d));
    tmax = fmaxf(tmax, __shfl_xor(tmax, 32));
    if (!__all(tmax <= mrow + 11.54f)) {        // defer-max (T13), 8*log2e
      float mnew = fmaxf(mrow, tmax);
      float alpha = fexp2(mrow - mnew);
      lrow *= alpha;
      float ar[16];
#pragma unroll
      for (int m = 0; m < 16; ++m) ar[m] = __shfl(alpha, (m & 3) + 8 * (m >> 2) + 4 * hi);
#pragma unroll
      for (int nf = 0; nf < 4; ++nf)
#pragma unroll
        for (int m = 0; m < 16; ++m) o4[nf][m] *= ar[m];
      mrow = mnew;
    }
#pragma unroll
    for (int m = 0; m < 16; ++m) st[m] = fexp2(st[m] - mrow);
    float s8[8];
#pragma unroll
    for (int m = 0; m < 8; ++m) s8[m] = st[m] + st[m + 8];
    float s4a = s8[0] + s8[4], s4b = s8[1] + s8[5], s4c = s8[2] + s8[6], s4d = s8[3] + s8[7];
    float psum = (s4a + s4b) + (s4c + s4d);
    psum += __shfl_xor(psum, 32);
    lrow += psum;

    // ---- P -> f16, re-fragment via permlane32_swap: 2 A-frags (kv chunks of 16) ----
    int Wd[8];
#pragma unroll
    for (int m = 0; m < 8; ++m) {
      unsigned l0 = __builtin_bit_cast(u16, (_Float16)st[2 * m]);
      unsigned h0 = __builtin_bit_cast(u16, (_Float16)st[2 * m + 1]);
      Wd[m] = (int)(l0 | (h0 << 16));
    }
    plswap(Wd[0], Wd[2]); plswap(Wd[1], Wd[3]);
    plswap(Wd[4], Wd[6]); plswap(Wd[5], Wd[7]);
    union PU { int w[4]; f16x8 v; };
    PU pa[2];
#pragma unroll
    for (int c = 0; c < 2; ++c) {
      pa[c].w[0] = Wd[c * 4 + 0]; pa[c].w[1] = Wd[c * 4 + 1];
      pa[c].w[2] = Wd[c * 4 + 2]; pa[c].w[3] = Wd[c * 4 + 3];
    }

    // ---- O += P.V over this wave's e-half (V(it) resident) ----
    __builtin_amdgcn_s_setprio(1);
#pragma unroll
    for (int nf = 0; nf < 4; ++nf) {
      int e = eh * 128 + nf * 32 + r31;
      const char* vrow = VB + ((e << 6) ^ ((e & 4) << 4));   // bit6 row-pair swap
      int swzv = (e & 3) << 4;
#pragma unroll
      for (int c = 0; c < 2; ++c) {
        f16x8 v = *reinterpret_cast<const f16x8*>(vrow + ((c * 32 + hi * 16) ^ swzv));
        o4[nf] = __builtin_amdgcn_mfma_f32_32x32x16_f16(pa[c].v, v, o4[nf], 0, 0, 0);
      }
    }
    __builtin_amdgcn_s_setprio(0);
  }

  // ---- epilogue: /(16*l) * inp, direct store (waves own disjoint 32q x 128e) ----
  float linv = 1.0f / (16.0f * lrow);
  float lr[16];
#pragma unroll
  for (int m = 0; m < 16; ++m) lr[m] = __shfl(linv, (m & 3) + 8 * (m >> 2) + 4 * hi);
  const long ob = (bN + qt * 64 + qg * 32) << 8;
#pragma unroll
  for (int nf = 0; nf < 4; ++nf)
#pragma unroll
    for (int m = 0; m < 16; ++m) {
      int qr = (m & 3) + 8 * (m >> 2) + 4 * hi;
      long off2 = ob + ((long)qr << 8) + eh * 128 + nf * 32 + r31;
      out[off2] = o4[nf][m] * lr[m] * inp[off2];
    }
}

// ---------------- host ----------------
// ws layout (bytes):
//   [0,   16M)  x1h f16
//   [16M, 32M)  x1T f16
//   [32M, 48M)  inF f16 (conv temp)
//   [48M, +1.2M) wT f16 (conv temp)
extern "C" void kernel_launch(void* const* d_in, const int* in_sizes, int n_in,
                              void* d_out, int out_size, void* d_ws, size_t ws_size,
                              hipStream_t stream) {
  const float* inp   = (const float*)d_in[0];
  const float* convw = (const float*)d_in[1];
  const float* convb = (const float*)d_in[2];
  float* out = (float*)d_out;
  char* ws = (char*)d_ws;

  u16* x1h = (u16*)(ws);                   // f16
  u16* x1T = (u16*)(ws + 16777216L);       // f16, transposed
  u16* inF = (u16*)(ws + 33554432L);       // f16 conv input
  u16* wT  = (u16*)(ws + 50331648L);       // f16 transposed weights

  k_prep<<<10496, 256, 0, stream>>>(inp, inF, convw, wT);
  k_conv<<<512, 256, 0, stream>>>(inF, wT, convb, x1h);
  k_trans<<<2048, 256, 0, stream>>>(x1h, x1T);
  k_flash3<<<512, 256, 0, stream>>>(x1h, x1T, inp, out);
}